// Round 23
// baseline (176.638 us; speedup 1.0000x reference)
//
#include <hip/hip_runtime.h>
#include <hip/hip_bf16.h>
#include <math.h>

#define BATCH   8
#define SEQLEN  4096
#define DMODEL  256
#define DSTATE  16
#define NHEADS  32
#define HEADDIM 16
#define DINNER  512
#define CONVDIM 544
#define DINPROJ 1088
#define NROWS   (BATCH*SEQLEN)
#define CHUNK   64
#define NCH     (SEQLEN/CHUNK)   // 64

typedef __attribute__((ext_vector_type(8))) short short8;
typedef __attribute__((ext_vector_type(8))) unsigned short ushort8;
typedef __attribute__((ext_vector_type(4))) float f32x4;

__device__ __forceinline__ float bfu2f(unsigned short u){
  union { float f; unsigned int i; } x; x.i = ((unsigned int)u) << 16; return x.f;
}
__device__ __forceinline__ unsigned short f2bfu(float f){
  union { float f; unsigned int u; } v; v.f = f;
  v.u += 0x7fffu + ((v.u >> 16) & 1u);
  return (unsigned short)(v.u >> 16);
}

// ---------------- prep: cast u to bf16 AND transpose+cast both weights ----------------
// blocks [0, NB_CAST): u cast (float4-wide). blocks [NB_CAST, NB_CAST+NB_TR): transposes.
#define NB_CAST (NROWS*DMODEL/1024)
#define NB_TR   ((DINPROJ*DMODEL + DINNER*DMODEL)/256)
__global__ __launch_bounds__(256) void k_prep(const float* __restrict__ u, unsigned short* __restrict__ ub,
                                              const float* __restrict__ Win,
                                              const float* __restrict__ Wout,
                                              unsigned short* __restrict__ WinT,
                                              unsigned short* __restrict__ WoutT){
  if (blockIdx.x < NB_CAST){
    int i = blockIdx.x*256 + threadIdx.x;
    float4 v = reinterpret_cast<const float4*>(u)[i];
    ushort4 o; o.x=f2bfu(v.x); o.y=f2bfu(v.y); o.z=f2bfu(v.z); o.w=f2bfu(v.w);
    reinterpret_cast<ushort4*>(ub)[i] = o;
  } else {
    int idx = (blockIdx.x - NB_CAST)*256 + threadIdx.x;
    const int N1 = DINPROJ*DMODEL;          // 278528
    if (idx < N1){
      int n = idx / DMODEL, k = idx - n*DMODEL;
      WinT[idx] = f2bfu(Win[(size_t)k*DINPROJ + n]);
    } else {
      int j = idx - N1;                     // < 131072
      int n = j / DINNER, k = j - n*DINNER;
      WoutT[j] = f2bfu(Wout[(size_t)k*DMODEL + n]);
    }
  }
}

// ---------------- bf16 MFMA GEMM: BK=64 single-buffer; NY y-tiles, XCD-grouped ----------------
// EPI==1 epilogue also fuses dt = softplus(v + dt_bias), da = exp(-exp(A_log)*dt).
template<int EPI, int WC, int K, int NY>
__global__ __launch_bounds__(WC*128) void k_gemm(
    const unsigned short* __restrict__ A,
    const unsigned short* __restrict__ BT,
    unsigned short* __restrict__ oz,
    unsigned short* __restrict__ oxbc,
    const float* __restrict__ dt_bias,
    const float* __restrict__ A_log,
    float* __restrict__ odtq,
    float* __restrict__ odaq,
    float* __restrict__ of32, int Nout)
{
  constexpr int BN      = WC*32;
  constexpr int THREADS = WC*128;
  constexpr int NAI     = 1024/THREADS;
  constexpr int NBI     = (BN*8)/THREADS;
  __shared__ uint4 lds[(128 + BN)*8];
  const int tid = threadIdx.x;
  const int l   = tid & 63;
  const int w   = tid >> 6;
  const int wr  = w & 1, wc = w >> 1;
  int bx, by;
  if (NY == 1){ bx = blockIdx.x; by = 0; }
  else {
    int flat = blockIdx.x;
    int xcd = flat & 7;
    int grp = flat >> 3;
    by = grp % NY;
    bx = (grp / NY)*8 + xcd;
  }
  const int bm0 = bx * 128;
  const int bn0 = by * BN;
  const int fr  = l & 15, kq = l >> 4;
  f32x4 acc[4][2] = {};
  const int nK = K >> 6;
  for (int kt = 0; kt < nK; ++kt){
    const int k0 = kt << 6;
    #pragma unroll
    for (int i = 0; i < NAI; ++i){
      int idx = tid + i*THREADS;
      int row = idx >> 3, slot = idx & 7;
      uint4 v = *reinterpret_cast<const uint4*>(A + (size_t)(bm0+row)*K + k0 + slot*8);
      lds[row*8 + (slot ^ (row & 7))] = v;
    }
    #pragma unroll
    for (int i = 0; i < NBI; ++i){
      int idx = tid + i*THREADS;
      int row = idx >> 3, slot = idx & 7;
      uint4 v = *reinterpret_cast<const uint4*>(BT + (size_t)(bn0+row)*K + k0 + slot*8);
      lds[1024 + row*8 + (slot ^ (row & 7))] = v;
    }
    __syncthreads();
    short8 bf[2][2];
    #pragma unroll
    for (int kk = 0; kk < 2; ++kk){
      #pragma unroll
      for (int nf = 0; nf < 2; ++nf){
        int rb = wc*32 + nf*16 + fr;
        bf[kk][nf] = *reinterpret_cast<const short8*>(&lds[1024 + rb*8 + ((kk*4 + kq) ^ (rb & 7))]);
      }
    }
    #pragma unroll
    for (int mf = 0; mf < 4; ++mf){
      int ra = wr*64 + mf*16 + fr;
      #pragma unroll
      for (int kk = 0; kk < 2; ++kk){
        short8 af = *reinterpret_cast<const short8*>(&lds[ra*8 + ((kk*4 + kq) ^ (ra & 7))]);
        #pragma unroll
        for (int nf = 0; nf < 2; ++nf)
          acc[mf][nf] = __builtin_amdgcn_mfma_f32_16x16x32_bf16(af, bf[kk][nf], acc[mf][nf], 0, 0, 0);
      }
    }
    __syncthreads();
  }
  #pragma unroll
  for (int mf = 0; mf < 4; ++mf){
    #pragma unroll
    for (int nf = 0; nf < 2; ++nf){
      #pragma unroll
      for (int r = 0; r < 4; ++r){
        int m = bm0 + wr*64 + mf*16 + kq*4 + r;
        int n = bn0 + wc*32 + nf*16 + fr;
        float v = acc[mf][nf][r];
        if (EPI == 1){
          if (n < DINNER)                 oz[(size_t)m*DINNER + n] = f2bfu(v);
          else if (n < DINNER + CONVDIM)  oxbc[(size_t)m*CONVDIM + (n - DINNER)] = f2bfu(v);
          else if (n < DINPROJ){
            int hh2 = n - DINNER - CONVDIM;
            float x = v + dt_bias[hh2];
            float dt = (x > 20.f) ? x : log1pf(expf(x));
            odtq[(size_t)m*NHEADS + hh2] = dt;
            odaq[(size_t)m*NHEADS + hh2] = expf(-expf(A_log[hh2]) * dt);
          }
          // n >= DINPROJ (pad tile): discard
        } else {
          of32[(size_t)m*Nout + n] = v;
        }
      }
    }
  }
}

// ---------------- conv+silu for B/C channels only ----------------
__global__ __launch_bounds__(256) void k_convbc(const unsigned short* __restrict__ xbc,
                                                const float* __restrict__ cw,
                                                const float* __restrict__ cb,
                                                float* __restrict__ bco){
  const int tid = threadIdx.x;
  const int j = tid & 31;
  const int rt = tid >> 5;
  const int r0 = blockIdx.x*64 + rt*8;
  const int ch = 512 + j;
  const int tloc = r0 & (SEQLEN-1);
  float wv0 = cw[ch*4+0], wv1 = cw[ch*4+1], wv2 = cw[ch*4+2], wv3 = cw[ch*4+3];
  const float bias = cb[ch];
  float xr[11];
  #pragma unroll
  for (int k = 0; k < 11; ++k){
    int r = r0 - 3 + k;
    xr[k] = (tloc - 3 + k < 0) ? 0.f : bfu2f(xbc[(size_t)r*CONVDIM + ch]);
  }
  #pragma unroll
  for (int i = 0; i < 8; ++i){
    float acc = fmaf(wv0, xr[i], fmaf(wv1, xr[i+1], fmaf(wv2, xr[i+2], fmaf(wv3, xr[i+3], bias))));
    bco[(size_t)(r0+i)*32 + j] = acc / (1.f + __expf(-acc));
  }
}

// ======== scan pass 1 (r11 form; y_local stored as bf16) ========
__global__ __launch_bounds__(256,4) void k_scan1(
    const unsigned short* __restrict__ xbc, const float* __restrict__ bc,
    const float* __restrict__ dta, const float* __restrict__ daa,
    const float* __restrict__ cwv, const float* __restrict__ cbv,
    const float* __restrict__ Dv,
    unsigned short* __restrict__ ylb, float* __restrict__ st, float* __restrict__ Pp)
{
  __shared__ float sBC[65*32];
  __shared__ float sdt[65*16];
  __shared__ float sda[65*16];
  const int tid = threadIdx.x;
  const int bid = blockIdx.x;
  const int qh = bid & 1;
  const int c  = (bid >> 1) & (NCH-1);
  const int b  = bid >> 7;
  const int w  = tid >> 6;
  const int l  = tid & 63;
  const int q  = qh*4 + w;
  const int hh = l >> 4, p = l & 15;
  const int h  = q*4 + hh;
  const size_t row0 = (size_t)b*SEQLEN + (size_t)c*CHUNK;
  const int xoff = q*64 + l;
  {
    const float* src = bc + row0*32;
    #pragma unroll
    for (int i = 0; i < 2; ++i){
      int idx = tid + i*256;
      *reinterpret_cast<float4*>(&sBC[idx*4]) = *reinterpret_cast<const float4*>(src + (size_t)idx*4);
    }
  }
  {
    int t = tid >> 2, g = (tid & 3)*4;
    *reinterpret_cast<float4*>(&sdt[t*16+g]) =
      *reinterpret_cast<const float4*>(dta + (row0+t)*NHEADS + qh*16 + g);
    *reinterpret_cast<float4*>(&sda[t*16+g]) =
      *reinterpret_cast<const float4*>(daa + (row0+t)*NHEADS + qh*16 + g);
  }
  const float cw0 = cwv[xoff*4+0], cw1 = cwv[xoff*4+1], cw2 = cwv[xoff*4+2], cw3 = cwv[xoff*4+3];
  const float cb0 = cbv[xoff];
  const float Dh = Dv[h];
  const int dIdx = w*4 + hh;
  float wA, wB, wC;
  if (c == 0){ wA = wB = wC = 0.f; }
  else {
    wA = bfu2f(xbc[(row0-3)*CONVDIM + xoff]);
    wB = bfu2f(xbc[(row0-2)*CONVDIM + xoff]);
    wC = bfu2f(xbc[(row0-1)*CONVDIM + xoff]);
  }
  float xq0 = bfu2f(xbc[(row0+0)*CONVDIM + xoff]);
  float xq1 = bfu2f(xbc[(row0+1)*CONVDIM + xoff]);
  float xq2 = bfu2f(xbc[(row0+2)*CONVDIM + xoff]);
  float xq3 = bfu2f(xbc[(row0+3)*CONVDIM + xoff]);
  __syncthreads();
  float BA[32], BB[32];
  #pragma unroll
  for (int k = 0; k < 8; ++k)
    *reinterpret_cast<float4*>(&BA[4*k]) = *reinterpret_cast<const float4*>(&sBC[4*k]);
  float dtA = sdt[dIdx], daA = sda[dIdx];
  float dtB, daB;
  float hs[16];
  #pragma unroll
  for (int n = 0; n < 16; ++n) hs[n] = 0.f;
  float cum = 1.f;

#define S1STEP(CUR, NXT, DTC, DAC, DTN, DAN, XQ, T) {                          \
    const int t_ = (T);                                                        \
    _Pragma("unroll")                                                          \
    for (int k = 0; k < 8; ++k)                                                \
      *reinterpret_cast<float4*>(&NXT[4*k]) =                                  \
        *reinterpret_cast<const float4*>(&sBC[(t_+1)*32 + 4*k]);               \
    DTN = sdt[(t_+1)*16 + dIdx]; DAN = sda[(t_+1)*16 + dIdx];                  \
    float xnew = bfu2f(xbc[(row0 + t_ + 4)*CONVDIM + xoff]);                   \
    float xc = fmaf(cw0, wA, fmaf(cw1, wB, fmaf(cw2, wC, fmaf(cw3, XQ, cb0))));\
    wA = wB; wB = wC; wC = XQ; XQ = xnew;                                      \
    float xs = xc / (1.f + __expf(-xc));                                       \
    float dx = DTC * xs;                                                       \
    float y_ = 0.f;                                                            \
    _Pragma("unroll")                                                          \
    for (int n = 0; n < 16; ++n) hs[n] = fmaf(DAC, hs[n], dx*CUR[n]);          \
    _Pragma("unroll")                                                          \
    for (int n = 0; n < 16; ++n) y_ = fmaf(hs[n], CUR[16+n], y_);              \
    cum *= DAC;                                                                \
    ylb[(row0 + t_)*DINNER + xoff] = f2bfu(y_ + Dh*xs);                        \
  }

  for (int T = 0; T < CHUNK; T += 4){
    S1STEP(BA, BB, dtA, daA, dtB, daB, xq0, T+0);
    S1STEP(BB, BA, dtB, daB, dtA, daA, xq1, T+1);
    S1STEP(BA, BB, dtA, daA, dtB, daB, xq2, T+2);
    S1STEP(BB, BA, dtB, daB, dtA, daA, xq3, T+3);
  }
#undef S1STEP
  float* sp = st + (((size_t)(b*NHEADS + h)*NCH + c)*16 + p)*16;
  #pragma unroll
  for (int k = 0; k < 4; ++k)
    *reinterpret_cast<float4*>(sp + 4*k) = make_float4(hs[4*k], hs[4*k+1], hs[4*k+2], hs[4*k+3]);
  if (p == 0) Pp[((size_t)b*NHEADS + h)*NCH + c] = cum;
}

// pass 2: inter-chunk scan; st[c] := hinit_c in place.
__global__ __launch_bounds__(64) void k_scan2(float* __restrict__ st, const float* __restrict__ Pp){
  const int bh = blockIdx.x;
  const int l = threadIdx.x;
  float* sb = st + (size_t)bh*NCH*256 + l*4;
  const float* pb = Pp + (size_t)bh*NCH;
  float4 carry = make_float4(0.f,0.f,0.f,0.f);
  float4 Hb[4]; float Pb[4];
  #pragma unroll
  for (int i = 0; i < 4; ++i){
    Hb[i] = *reinterpret_cast<const float4*>(sb + (size_t)i*256);
    Pb[i] = pb[i];
  }
  for (int c0 = 0; c0 < NCH; c0 += 4){
    #pragma unroll
    for (int i = 0; i < 4; ++i){
      const int cc = c0 + i;
      float4 Hc = Hb[i]; float Pc = Pb[i];
      if (cc + 4 < NCH){
        Hb[i] = *reinterpret_cast<const float4*>(sb + (size_t)(cc+4)*256);
        Pb[i] = pb[cc+4];
      }
      *reinterpret_cast<float4*>(sb + (size_t)cc*256) = carry;
      carry.x = fmaf(Pc, carry.x, Hc.x);
      carry.y = fmaf(Pc, carry.y, Hc.y);
      carry.z = fmaf(Pc, carry.z, Hc.z);
      carry.w = fmaf(Pc, carry.w, Hc.w);
    }
  }
}

// ======== pass 3 fused gate+RMSNorm, half-chunk split; tree cum ========
__global__ __launch_bounds__(512) void k_scan3g(
    const unsigned short* __restrict__ ylb, const float* __restrict__ bc,
    const float* __restrict__ daa, const float* __restrict__ st,
    unsigned short* __restrict__ zbf, const float* __restrict__ nw)
{
  __shared__ float sC[65*16];
  __shared__ float sda[65*32];
  __shared__ float sred[2][4][8];
  const int tid = threadIdx.x;
  const int bid = blockIdx.x;     // ((b*NCH + c)<<1) | half
  const int half = bid & 1;
  const int c = (bid >> 1) & (NCH-1);
  const int b = bid >> 7;
  const int T0 = half*32;
  const int w = tid >> 6;
  const int l = tid & 63;
  const int hh = l >> 4, p = l & 15;
  const int h = w*4 + hh;
  const size_t row0 = (size_t)b*SEQLEN + (size_t)c*CHUNK;
  const int xoff = w*64 + l;
  if (tid < 256){
    int t = tid >> 2, g = (tid & 3)*4;
    *reinterpret_cast<float4*>(&sC[t*16+g]) =
      *reinterpret_cast<const float4*>(bc + (row0+t)*32 + 16 + g);
  } else {
    int j = tid - 256;
    #pragma unroll
    for (int kk = 0; kk < 2; ++kk){
      int idx = j*2 + kk;
      int t = idx >> 3, g = (idx & 7)*4;
      *reinterpret_cast<float4*>(&sda[t*32+g]) =
        *reinterpret_cast<const float4*>(daa + (row0+t)*NHEADS + g);
    }
  }
  float hi[16];
  {
    const float* sp = st + (((size_t)(b*NHEADS + h)*NCH + c)*16 + p)*16;
    #pragma unroll
    for (int k = 0; k < 4; ++k){
      float4 v = *reinterpret_cast<const float4*>(sp + 4*k);
      hi[4*k] = v.x; hi[4*k+1] = v.y; hi[4*k+2] = v.z; hi[4*k+3] = v.w;
    }
  }
  const float nwv = nw[xoff];
  float yq0 = bfu2f(ylb[(row0+T0+0)*DINNER + xoff]);
  float yq1 = bfu2f(ylb[(row0+T0+1)*DINNER + xoff]);
  float yq2 = bfu2f(ylb[(row0+T0+2)*DINNER + xoff]);
  float yq3 = bfu2f(ylb[(row0+T0+3)*DINNER + xoff]);
  float zq0 = bfu2f(zbf[(row0+T0+0)*DINNER + xoff]);
  float zq1 = bfu2f(zbf[(row0+T0+1)*DINNER + xoff]);
  float zq2 = bfu2f(zbf[(row0+T0+2)*DINNER + xoff]);
  float zq3 = bfu2f(zbf[(row0+T0+3)*DINNER + xoff]);
  __syncthreads();
  float cum = 1.f;
  if (T0){
    float c0=1.f, c1=1.f, c2=1.f, c3=1.f;
    #pragma unroll
    for (int t = 0; t < 32; t += 4){
      c0 *= sda[(t+0)*32 + h];
      c1 *= sda[(t+1)*32 + h];
      c2 *= sda[(t+2)*32 + h];
      c3 *= sda[(t+3)*32 + h];
    }
    cum = (c0*c1)*(c2*c3);
  }
  float CA[16], CB[16];
  #pragma unroll
  for (int k = 0; k < 4; ++k)
    *reinterpret_cast<float4*>(&CA[4*k]) = *reinterpret_cast<const float4*>(&sC[T0*16 + 4*k]);
  float daA = sda[T0*32 + h], daB;

#define S3STEP(CUR, NXT, DAC, DAN, YQ, ZQ, TV, PS, T) {                        \
    const int t_ = (T);                                                        \
    _Pragma("unroll")                                                          \
    for (int k = 0; k < 4; ++k)                                                \
      *reinterpret_cast<float4*>(&NXT[4*k]) =                                  \
        *reinterpret_cast<const float4*>(&sC[(t_+1)*16 + 4*k]);                \
    DAN = sda[(t_+1)*32 + h];                                                  \
    float ynew = bfu2f(ylb[(row0 + t_ + 4)*DINNER + xoff]);                    \
    float znew = bfu2f(zbf[(row0 + t_ + 4)*DINNER + xoff]);                    \
    cum *= DAC;                                                                \
    float corr = 0.f;                                                          \
    _Pragma("unroll")                                                          \
    for (int n = 0; n < 16; ++n) corr = fmaf(hi[n], CUR[n], corr);             \
    float yv = YQ + cum*corr;                                                  \
    float sg = ZQ / (1.f + __expf(-ZQ));                                       \
    TV = yv * sg; PS = TV*TV;                                                  \
    YQ = ynew; ZQ = znew;                                                      \
  }

  for (int T = T0; T < T0 + 32; T += 4){
    float tv0, tv1, tv2, tv3, ps0, ps1, ps2, ps3;
    S3STEP(CA, CB, daA, daB, yq0, zq0, tv0, ps0, T+0);
    S3STEP(CB, CA, daB, daA, yq1, zq1, tv1, ps1, T+1);
    S3STEP(CA, CB, daA, daB, yq2, zq2, tv2, ps2, T+2);
    S3STEP(CB, CA, daB, daA, yq3, zq3, tv3, ps3, T+3);
    #pragma unroll
    for (int m = 1; m <= 32; m <<= 1){
      ps0 += __shfl_xor(ps0, m, 64);
      ps1 += __shfl_xor(ps1, m, 64);
      ps2 += __shfl_xor(ps2, m, 64);
      ps3 += __shfl_xor(ps3, m, 64);
    }
    const int gb = (T >> 2) & 1;
    if (l == 0){
      sred[gb][0][w] = ps0; sred[gb][1][w] = ps1;
      sred[gb][2][w] = ps2; sred[gb][3][w] = ps3;
    }
    __syncthreads();
    float ss[4];
    #pragma unroll
    for (int i = 0; i < 4; ++i){
      float4 ra = *reinterpret_cast<const float4*>(&sred[gb][i][0]);
      float4 rb = *reinterpret_cast<const float4*>(&sred[gb][i][4]);
      ss[i] = (ra.x+ra.y)+(ra.z+ra.w)+((rb.x+rb.y)+(rb.z+rb.w));
    }
    unsigned short* zp = zbf + (row0 + T)*DINNER + xoff;
    zp[0*DINNER] = f2bfu(tv0 * rsqrtf(ss[0]*(1.f/DINNER) + 1e-5f) * nwv);
    zp[1*DINNER] = f2bfu(tv1 * rsqrtf(ss[1]*(1.f/DINNER) + 1e-5f) * nwv);
    zp[2*DINNER] = f2bfu(tv2 * rsqrtf(ss[2]*(1.f/DINNER) + 1e-5f) * nwv);
    zp[3*DINNER] = f2bfu(tv3 * rsqrtf(ss[3]*(1.f/DINNER) + 1e-5f) * nwv);
  }
#undef S3STEP
}

extern "C" void kernel_launch(void* const* d_in, const int* in_sizes, int n_in,
                              void* d_out, int out_size, void* d_ws, size_t ws_size,
                              hipStream_t stream)
{
  const float* u       = (const float*)d_in[0];
  const float* W_in    = (const float*)d_in[1];
  const float* conv_w  = (const float*)d_in[2];
  const float* conv_b  = (const float*)d_in[3];
  const float* dt_bias = (const float*)d_in[4];
  const float* A_log   = (const float*)d_in[5];
  const float* Dvec    = (const float*)d_in[6];
  const float* norm_w  = (const float*)d_in[7];
  const float* W_out   = (const float*)d_in[8];
  float* out = (float*)d_out;
  char* ws = (char*)d_ws;

  unsigned short* ubf   = (unsigned short*)(ws + 0);          // 16,777,216 B (dead after GEMM1)
  float* chst           = (float*)(ws + 0);                   // 16,777,216 B (scan, overlaps ubf)
  unsigned short* wintT = (unsigned short*)(ws + 16777216);   //    589,824 B (1152 rows: 64 pad)
  unsigned short* woutT = (unsigned short*)(ws + 17367040);   //    262,144 B
  unsigned short* zbf   = (unsigned short*)(ws + 17629184);   // 33,554,432 B (becomes t after scan3g)
  unsigned short* xbcbf = (unsigned short*)(ws + 51183616);   // 35,651,584 B
  float* Pp             = (float*)(ws + 86835200);            //     65,536 B
  unsigned short* ylb   = (unsigned short*)(ws + 91029504);   // 33,554,432 B (bf16 y_local)
  float* convoBC        = (float*)(ws + 124583936);           //  4,194,304 B
  float* dtq            = (float*)(ws + 128778240);           //  4,194,304 B
  float* daq            = (float*)(ws + 132972544);           //  4,194,304 B  (total 137,166,848 B)

  k_prep<<<NB_CAST + NB_TR, 256, 0, stream>>>(u, ubf, W_in, W_out, wintT, woutT);

  // GEMM1: all 1088 cols as 9 y-tiles of 128 (tile 8 half-pad, stores masked);
  // dt/dA fused into epilogue.
  k_gemm<1,4,DMODEL,9><<<(NROWS/128)*9, 512, 0, stream>>>(ubf, wintT, zbf, xbcbf,
                                                          dt_bias, A_log, dtq, daq, nullptr, 0);

  k_convbc<<<NROWS/64, 256, 0, stream>>>(xbcbf, conv_w, conv_b, convoBC);

  k_scan1<<<BATCH*2*NCH, 256, 0, stream>>>(xbcbf, convoBC, dtq, daq, conv_w, conv_b, Dvec,
                                           ylb, chst, Pp);
  k_scan2<<<BATCH*NHEADS, 64, 0, stream>>>(chst, Pp);
  k_scan3g<<<BATCH*NCH*2, 512, 0, stream>>>(ylb, convoBC, daq, chst, zbf, norm_w);

  // GEMM2: N=256 as 2 y-tiles, XCD-grouped
  k_gemm<2,4,DINNER,2><<<(NROWS/128)*2, 512, 0, stream>>>(zbf, woutT, nullptr, nullptr,
                                                          nullptr, nullptr, nullptr, nullptr, out, DMODEL);
}

// Round 24
// 160.277 us; speedup vs baseline: 1.1021x; 1.1021x over previous
//
#include <hip/hip_runtime.h>
#include <hip/hip_bf16.h>
#include <math.h>

#define BATCH   8
#define SEQLEN  4096
#define DMODEL  256
#define DSTATE  16
#define NHEADS  32
#define HEADDIM 16
#define DINNER  512
#define CONVDIM 544
#define DINPROJ 1088
#define NROWS   (BATCH*SEQLEN)
#define CHUNK   64
#define NCH     (SEQLEN/CHUNK)   // 64

typedef __attribute__((ext_vector_type(8))) short short8;
typedef __attribute__((ext_vector_type(8))) unsigned short ushort8;
typedef __attribute__((ext_vector_type(4))) float f32x4;

__device__ __forceinline__ float bfu2f(unsigned short u){
  union { float f; unsigned int i; } x; x.i = ((unsigned int)u) << 16; return x.f;
}
__device__ __forceinline__ unsigned short f2bfu(float f){
  union { float f; unsigned int u; } v; v.f = f;
  v.u += 0x7fffu + ((v.u >> 16) & 1u);
  return (unsigned short)(v.u >> 16);
}

// ---------------- prep: cast u to bf16 ----------------
__global__ __launch_bounds__(256) void k_cast_u(const float* __restrict__ u, unsigned short* __restrict__ ub){
  int i = blockIdx.x*256 + threadIdx.x;
  float4 v = reinterpret_cast<const float4*>(u)[i];
  ushort4 o; o.x=f2bfu(v.x); o.y=f2bfu(v.y); o.z=f2bfu(v.z); o.w=f2bfu(v.w);
  reinterpret_cast<ushort4*>(ub)[i] = o;
}

// ---------------- prep: transpose+cast BOTH weights in one launch ----------------
__global__ __launch_bounds__(256) void k_transpose2(const float* __restrict__ Win,
                                                    const float* __restrict__ Wout,
                                                    unsigned short* __restrict__ WinT,
                                                    unsigned short* __restrict__ WoutT){
  int idx = blockIdx.x*256 + threadIdx.x;
  const int N1 = DINPROJ*DMODEL;          // 278528
  if (idx < N1){
    int n = idx / DMODEL, k = idx - n*DMODEL;
    WinT[idx] = f2bfu(Win[(size_t)k*DINPROJ + n]);
  } else {
    int j = idx - N1;                     // < 131072
    int n = j / DINNER, k = j - n*DINNER;
    WoutT[j] = f2bfu(Wout[(size_t)k*DMODEL + n]);
  }
}

// ---------------- bf16 MFMA GEMM: BK=64 single-buffer; NY y-tiles, XCD-grouped ----------------
template<int EPI, int WC, int K, int NY>
__global__ __launch_bounds__(WC*128) void k_gemm(
    const unsigned short* __restrict__ A,
    const unsigned short* __restrict__ BT,
    unsigned short* __restrict__ oz,
    unsigned short* __restrict__ oxbc,
    float* __restrict__ odtraw,
    float* __restrict__ of32, int Nout)
{
  constexpr int BN      = WC*32;
  constexpr int THREADS = WC*128;
  constexpr int NAI     = 1024/THREADS;
  constexpr int NBI     = (BN*8)/THREADS;
  __shared__ uint4 lds[(128 + BN)*8];
  const int tid = threadIdx.x;
  const int l   = tid & 63;
  const int w   = tid >> 6;
  const int wr  = w & 1, wc = w >> 1;
  int bx, by;
  if (NY == 1){ bx = blockIdx.x; by = 0; }
  else {
    int flat = blockIdx.x;
    int xcd = flat & 7;
    int grp = flat >> 3;
    by = grp % NY;
    bx = (grp / NY)*8 + xcd;
  }
  const int bm0 = bx * 128;
  const int bn0 = by * BN;
  const int fr  = l & 15, kq = l >> 4;
  f32x4 acc[4][2] = {};
  const int nK = K >> 6;
  for (int kt = 0; kt < nK; ++kt){
    const int k0 = kt << 6;
    #pragma unroll
    for (int i = 0; i < NAI; ++i){
      int idx = tid + i*THREADS;
      int row = idx >> 3, slot = idx & 7;
      uint4 v = *reinterpret_cast<const uint4*>(A + (size_t)(bm0+row)*K + k0 + slot*8);
      lds[row*8 + (slot ^ (row & 7))] = v;
    }
    #pragma unroll
    for (int i = 0; i < NBI; ++i){
      int idx = tid + i*THREADS;
      int row = idx >> 3, slot = idx & 7;
      uint4 v = *reinterpret_cast<const uint4*>(BT + (size_t)(bn0+row)*K + k0 + slot*8);
      lds[1024 + row*8 + (slot ^ (row & 7))] = v;
    }
    __syncthreads();
    short8 bf[2][2];
    #pragma unroll
    for (int kk = 0; kk < 2; ++kk){
      #pragma unroll
      for (int nf = 0; nf < 2; ++nf){
        int rb = wc*32 + nf*16 + fr;
        bf[kk][nf] = *reinterpret_cast<const short8*>(&lds[1024 + rb*8 + ((kk*4 + kq) ^ (rb & 7))]);
      }
    }
    #pragma unroll
    for (int mf = 0; mf < 4; ++mf){
      int ra = wr*64 + mf*16 + fr;
      #pragma unroll
      for (int kk = 0; kk < 2; ++kk){
        short8 af = *reinterpret_cast<const short8*>(&lds[ra*8 + ((kk*4 + kq) ^ (ra & 7))]);
        #pragma unroll
        for (int nf = 0; nf < 2; ++nf)
          acc[mf][nf] = __builtin_amdgcn_mfma_f32_16x16x32_bf16(af, bf[kk][nf], acc[mf][nf], 0, 0, 0);
      }
    }
    __syncthreads();
  }
  #pragma unroll
  for (int mf = 0; mf < 4; ++mf){
    #pragma unroll
    for (int nf = 0; nf < 2; ++nf){
      #pragma unroll
      for (int r = 0; r < 4; ++r){
        int m = bm0 + wr*64 + mf*16 + kq*4 + r;
        int n = bn0 + wc*32 + nf*16 + fr;
        float v = acc[mf][nf][r];
        if (EPI == 1){
          if (n < DINNER)                 oz[(size_t)m*DINNER + n] = f2bfu(v);
          else if (n < DINNER + CONVDIM)  oxbc[(size_t)m*CONVDIM + (n - DINNER)] = f2bfu(v);
          else if (n < DINPROJ)           odtraw[(size_t)m*NHEADS + (n - DINNER - CONVDIM)] = v;
          // n >= DINPROJ (pad tile): discard
        } else {
          of32[(size_t)m*Nout + n] = v;
        }
      }
    }
  }
}

// ---------------- merged: conv+silu (B/C channels) AND dt/dA precompute ----------------
__global__ __launch_bounds__(256) void k_convdt(const unsigned short* __restrict__ xbc,
                                                const float* __restrict__ cw,
                                                const float* __restrict__ cb,
                                                float* __restrict__ bco,
                                                const float* __restrict__ dtraw,
                                                const float* __restrict__ dt_bias,
                                                const float* __restrict__ A_log,
                                                float* __restrict__ dt_o,
                                                float* __restrict__ dA_o){
  const int tid = threadIdx.x;
  if (blockIdx.x < NROWS/64){
    const int j = tid & 31;
    const int rt = tid >> 5;
    const int r0 = blockIdx.x*64 + rt*8;
    const int ch = 512 + j;
    const int tloc = r0 & (SEQLEN-1);
    float wv0 = cw[ch*4+0], wv1 = cw[ch*4+1], wv2 = cw[ch*4+2], wv3 = cw[ch*4+3];
    const float bias = cb[ch];
    float xr[11];
    #pragma unroll
    for (int k = 0; k < 11; ++k){
      int r = r0 - 3 + k;
      xr[k] = (tloc - 3 + k < 0) ? 0.f : bfu2f(xbc[(size_t)r*CONVDIM + ch]);
    }
    #pragma unroll
    for (int i = 0; i < 8; ++i){
      float acc = fmaf(wv0, xr[i], fmaf(wv1, xr[i+1], fmaf(wv2, xr[i+2], fmaf(wv3, xr[i+3], bias))));
      bco[(size_t)(r0+i)*32 + j] = acc / (1.f + __expf(-acc));
    }
  } else {
    int i = (blockIdx.x - NROWS/64)*256 + tid;   // NROWS*NHEADS
    int h = i & (NHEADS-1);
    float x = dtraw[i] + dt_bias[h];
    float dt = (x > 20.f) ? x : log1pf(expf(x));
    dt_o[i] = dt;
    dA_o[i] = expf(-expf(A_log[h]) * dt);
  }
}

// ======== scan pass 1 (r11 form; y_local stored as bf16) ========
__global__ __launch_bounds__(256,4) void k_scan1(
    const unsigned short* __restrict__ xbc, const float* __restrict__ bc,
    const float* __restrict__ dta, const float* __restrict__ daa,
    const float* __restrict__ cwv, const float* __restrict__ cbv,
    const float* __restrict__ Dv,
    unsigned short* __restrict__ ylb, float* __restrict__ st, float* __restrict__ Pp)
{
  __shared__ float sBC[65*32];
  __shared__ float sdt[65*16];
  __shared__ float sda[65*16];
  const int tid = threadIdx.x;
  const int bid = blockIdx.x;
  const int qh = bid & 1;
  const int c  = (bid >> 1) & (NCH-1);
  const int b  = bid >> 7;
  const int w  = tid >> 6;
  const int l  = tid & 63;
  const int q  = qh*4 + w;
  const int hh = l >> 4, p = l & 15;
  const int h  = q*4 + hh;
  const size_t row0 = (size_t)b*SEQLEN + (size_t)c*CHUNK;
  const int xoff = q*64 + l;
  {
    const float* src = bc + row0*32;
    #pragma unroll
    for (int i = 0; i < 2; ++i){
      int idx = tid + i*256;
      *reinterpret_cast<float4*>(&sBC[idx*4]) = *reinterpret_cast<const float4*>(src + (size_t)idx*4);
    }
  }
  {
    int t = tid >> 2, g = (tid & 3)*4;
    *reinterpret_cast<float4*>(&sdt[t*16+g]) =
      *reinterpret_cast<const float4*>(dta + (row0+t)*NHEADS + qh*16 + g);
    *reinterpret_cast<float4*>(&sda[t*16+g]) =
      *reinterpret_cast<const float4*>(daa + (row0+t)*NHEADS + qh*16 + g);
  }
  const float cw0 = cwv[xoff*4+0], cw1 = cwv[xoff*4+1], cw2 = cwv[xoff*4+2], cw3 = cwv[xoff*4+3];
  const float cb0 = cbv[xoff];
  const float Dh = Dv[h];
  const int dIdx = w*4 + hh;
  float wA, wB, wC;
  if (c == 0){ wA = wB = wC = 0.f; }
  else {
    wA = bfu2f(xbc[(row0-3)*CONVDIM + xoff]);
    wB = bfu2f(xbc[(row0-2)*CONVDIM + xoff]);
    wC = bfu2f(xbc[(row0-1)*CONVDIM + xoff]);
  }
  float xq0 = bfu2f(xbc[(row0+0)*CONVDIM + xoff]);
  float xq1 = bfu2f(xbc[(row0+1)*CONVDIM + xoff]);
  float xq2 = bfu2f(xbc[(row0+2)*CONVDIM + xoff]);
  float xq3 = bfu2f(xbc[(row0+3)*CONVDIM + xoff]);
  __syncthreads();
  float BA[32], BB[32];
  #pragma unroll
  for (int k = 0; k < 8; ++k)
    *reinterpret_cast<float4*>(&BA[4*k]) = *reinterpret_cast<const float4*>(&sBC[4*k]);
  float dtA = sdt[dIdx], daA = sda[dIdx];
  float dtB, daB;
  float hs[16];
  #pragma unroll
  for (int n = 0; n < 16; ++n) hs[n] = 0.f;
  float cum = 1.f;

#define S1STEP(CUR, NXT, DTC, DAC, DTN, DAN, XQ, T) {                          \
    const int t_ = (T);                                                        \
    _Pragma("unroll")                                                          \
    for (int k = 0; k < 8; ++k)                                                \
      *reinterpret_cast<float4*>(&NXT[4*k]) =                                  \
        *reinterpret_cast<const float4*>(&sBC[(t_+1)*32 + 4*k]);               \
    DTN = sdt[(t_+1)*16 + dIdx]; DAN = sda[(t_+1)*16 + dIdx];                  \
    float xnew = bfu2f(xbc[(row0 + t_ + 4)*CONVDIM + xoff]);                   \
    float xc = fmaf(cw0, wA, fmaf(cw1, wB, fmaf(cw2, wC, fmaf(cw3, XQ, cb0))));\
    wA = wB; wB = wC; wC = XQ; XQ = xnew;                                      \
    float xs = xc / (1.f + __expf(-xc));                                       \
    float dx = DTC * xs;                                                       \
    float y_ = 0.f;                                                            \
    _Pragma("unroll")                                                          \
    for (int n = 0; n < 16; ++n) hs[n] = fmaf(DAC, hs[n], dx*CUR[n]);          \
    _Pragma("unroll")                                                          \
    for (int n = 0; n < 16; ++n) y_ = fmaf(hs[n], CUR[16+n], y_);              \
    cum *= DAC;                                                                \
    ylb[(row0 + t_)*DINNER + xoff] = f2bfu(y_ + Dh*xs);                        \
  }

  for (int T = 0; T < CHUNK; T += 4){
    S1STEP(BA, BB, dtA, daA, dtB, daB, xq0, T+0);
    S1STEP(BB, BA, dtB, daB, dtA, daA, xq1, T+1);
    S1STEP(BA, BB, dtA, daA, dtB, daB, xq2, T+2);
    S1STEP(BB, BA, dtB, daB, dtA, daA, xq3, T+3);
  }
#undef S1STEP
  float* sp = st + (((size_t)(b*NHEADS + h)*NCH + c)*16 + p)*16;
  #pragma unroll
  for (int k = 0; k < 4; ++k)
    *reinterpret_cast<float4*>(sp + 4*k) = make_float4(hs[4*k], hs[4*k+1], hs[4*k+2], hs[4*k+3]);
  if (p == 0) Pp[((size_t)b*NHEADS + h)*NCH + c] = cum;
}

// pass 2: inter-chunk scan; st[c] := hinit_c in place.
__global__ __launch_bounds__(64) void k_scan2(float* __restrict__ st, const float* __restrict__ Pp){
  const int bh = blockIdx.x;
  const int l = threadIdx.x;
  float* sb = st + (size_t)bh*NCH*256 + l*4;
  const float* pb = Pp + (size_t)bh*NCH;
  float4 carry = make_float4(0.f,0.f,0.f,0.f);
  float4 Hb[4]; float Pb[4];
  #pragma unroll
  for (int i = 0; i < 4; ++i){
    Hb[i] = *reinterpret_cast<const float4*>(sb + (size_t)i*256);
    Pb[i] = pb[i];
  }
  for (int c0 = 0; c0 < NCH; c0 += 4){
    #pragma unroll
    for (int i = 0; i < 4; ++i){
      const int cc = c0 + i;
      float4 Hc = Hb[i]; float Pc = Pb[i];
      if (cc + 4 < NCH){
        Hb[i] = *reinterpret_cast<const float4*>(sb + (size_t)(cc+4)*256);
        Pb[i] = pb[cc+4];
      }
      *reinterpret_cast<float4*>(sb + (size_t)cc*256) = carry;
      carry.x = fmaf(Pc, carry.x, Hc.x);
      carry.y = fmaf(Pc, carry.y, Hc.y);
      carry.z = fmaf(Pc, carry.z, Hc.z);
      carry.w = fmaf(Pc, carry.w, Hc.w);
    }
  }
}

// ======== pass 3 fused gate+RMSNorm, half-chunk split; tree cum ========
__global__ __launch_bounds__(512) void k_scan3g(
    const unsigned short* __restrict__ ylb, const float* __restrict__ bc,
    const float* __restrict__ daa, const float* __restrict__ st,
    unsigned short* __restrict__ zbf, const float* __restrict__ nw)
{
  __shared__ float sC[65*16];
  __shared__ float sda[65*32];
  __shared__ float sred[2][4][8];
  const int tid = threadIdx.x;
  const int bid = blockIdx.x;     // ((b*NCH + c)<<1) | half
  const int half = bid & 1;
  const int c = (bid >> 1) & (NCH-1);
  const int b = bid >> 7;
  const int T0 = half*32;
  const int w = tid >> 6;
  const int l = tid & 63;
  const int hh = l >> 4, p = l & 15;
  const int h = w*4 + hh;
  const size_t row0 = (size_t)b*SEQLEN + (size_t)c*CHUNK;
  const int xoff = w*64 + l;
  if (tid < 256){
    int t = tid >> 2, g = (tid & 3)*4;
    *reinterpret_cast<float4*>(&sC[t*16+g]) =
      *reinterpret_cast<const float4*>(bc + (row0+t)*32 + 16 + g);
  } else {
    int j = tid - 256;
    #pragma unroll
    for (int kk = 0; kk < 2; ++kk){
      int idx = j*2 + kk;
      int t = idx >> 3, g = (idx & 7)*4;
      *reinterpret_cast<float4*>(&sda[t*32+g]) =
        *reinterpret_cast<const float4*>(daa + (row0+t)*NHEADS + g);
    }
  }
  float hi[16];
  {
    const float* sp = st + (((size_t)(b*NHEADS + h)*NCH + c)*16 + p)*16;
    #pragma unroll
    for (int k = 0; k < 4; ++k){
      float4 v = *reinterpret_cast<const float4*>(sp + 4*k);
      hi[4*k] = v.x; hi[4*k+1] = v.y; hi[4*k+2] = v.z; hi[4*k+3] = v.w;
    }
  }
  const float nwv = nw[xoff];
  float yq0 = bfu2f(ylb[(row0+T0+0)*DINNER + xoff]);
  float yq1 = bfu2f(ylb[(row0+T0+1)*DINNER + xoff]);
  float yq2 = bfu2f(ylb[(row0+T0+2)*DINNER + xoff]);
  float yq3 = bfu2f(ylb[(row0+T0+3)*DINNER + xoff]);
  float zq0 = bfu2f(zbf[(row0+T0+0)*DINNER + xoff]);
  float zq1 = bfu2f(zbf[(row0+T0+1)*DINNER + xoff]);
  float zq2 = bfu2f(zbf[(row0+T0+2)*DINNER + xoff]);
  float zq3 = bfu2f(zbf[(row0+T0+3)*DINNER + xoff]);
  __syncthreads();
  float cum = 1.f;
  if (T0){
    float c0=1.f, c1=1.f, c2=1.f, c3=1.f;
    #pragma unroll
    for (int t = 0; t < 32; t += 4){
      c0 *= sda[(t+0)*32 + h];
      c1 *= sda[(t+1)*32 + h];
      c2 *= sda[(t+2)*32 + h];
      c3 *= sda[(t+3)*32 + h];
    }
    cum = (c0*c1)*(c2*c3);
  }
  float CA[16], CB[16];
  #pragma unroll
  for (int k = 0; k < 4; ++k)
    *reinterpret_cast<float4*>(&CA[4*k]) = *reinterpret_cast<const float4*>(&sC[T0*16 + 4*k]);
  float daA = sda[T0*32 + h], daB;

#define S3STEP(CUR, NXT, DAC, DAN, YQ, ZQ, TV, PS, T) {                        \
    const int t_ = (T);                                                        \
    _Pragma("unroll")                                                          \
    for (int k = 0; k < 4; ++k)                                                \
      *reinterpret_cast<float4*>(&NXT[4*k]) =                                  \
        *reinterpret_cast<const float4*>(&sC[(t_+1)*16 + 4*k]);                \
    DAN = sda[(t_+1)*32 + h];                                                  \
    float ynew = bfu2f(ylb[(row0 + t_ + 4)*DINNER + xoff]);                    \
    float znew = bfu2f(zbf[(row0 + t_ + 4)*DINNER + xoff]);                    \
    cum *= DAC;                                                                \
    float corr = 0.f;                                                          \
    _Pragma("unroll")                                                          \
    for (int n = 0; n < 16; ++n) corr = fmaf(hi[n], CUR[n], corr);             \
    float yv = YQ + cum*corr;                                                  \
    float sg = ZQ / (1.f + __expf(-ZQ));                                       \
    TV = yv * sg; PS = TV*TV;                                                  \
    YQ = ynew; ZQ = znew;                                                      \
  }

  for (int T = T0; T < T0 + 32; T += 4){
    float tv0, tv1, tv2, tv3, ps0, ps1, ps2, ps3;
    S3STEP(CA, CB, daA, daB, yq0, zq0, tv0, ps0, T+0);
    S3STEP(CB, CA, daB, daA, yq1, zq1, tv1, ps1, T+1);
    S3STEP(CA, CB, daA, daB, yq2, zq2, tv2, ps2, T+2);
    S3STEP(CB, CA, daB, daA, yq3, zq3, tv3, ps3, T+3);
    #pragma unroll
    for (int m = 1; m <= 32; m <<= 1){
      ps0 += __shfl_xor(ps0, m, 64);
      ps1 += __shfl_xor(ps1, m, 64);
      ps2 += __shfl_xor(ps2, m, 64);
      ps3 += __shfl_xor(ps3, m, 64);
    }
    const int gb = (T >> 2) & 1;
    if (l == 0){
      sred[gb][0][w] = ps0; sred[gb][1][w] = ps1;
      sred[gb][2][w] = ps2; sred[gb][3][w] = ps3;
    }
    __syncthreads();
    float ss[4];
    #pragma unroll
    for (int i = 0; i < 4; ++i){
      float4 ra = *reinterpret_cast<const float4*>(&sred[gb][i][0]);
      float4 rb = *reinterpret_cast<const float4*>(&sred[gb][i][4]);
      ss[i] = (ra.x+ra.y)+(ra.z+ra.w)+((rb.x+rb.y)+(rb.z+rb.w));
    }
    unsigned short* zp = zbf + (row0 + T)*DINNER + xoff;
    zp[0*DINNER] = f2bfu(tv0 * rsqrtf(ss[0]*(1.f/DINNER) + 1e-5f) * nwv);
    zp[1*DINNER] = f2bfu(tv1 * rsqrtf(ss[1]*(1.f/DINNER) + 1e-5f) * nwv);
    zp[2*DINNER] = f2bfu(tv2 * rsqrtf(ss[2]*(1.f/DINNER) + 1e-5f) * nwv);
    zp[3*DINNER] = f2bfu(tv3 * rsqrtf(ss[3]*(1.f/DINNER) + 1e-5f) * nwv);
  }
#undef S3STEP
}

extern "C" void kernel_launch(void* const* d_in, const int* in_sizes, int n_in,
                              void* d_out, int out_size, void* d_ws, size_t ws_size,
                              hipStream_t stream)
{
  const float* u       = (const float*)d_in[0];
  const float* W_in    = (const float*)d_in[1];
  const float* conv_w  = (const float*)d_in[2];
  const float* conv_b  = (const float*)d_in[3];
  const float* dt_bias = (const float*)d_in[4];
  const float* A_log   = (const float*)d_in[5];
  const float* Dvec    = (const float*)d_in[6];
  const float* norm_w  = (const float*)d_in[7];
  const float* W_out   = (const float*)d_in[8];
  float* out = (float*)d_out;
  char* ws = (char*)d_ws;

  unsigned short* ubf   = (unsigned short*)(ws + 0);          // 16,777,216 B (dead after GEMM1)
  float* chst           = (float*)(ws + 0);                   // 16,777,216 B (scan, overlaps ubf)
  unsigned short* wintT = (unsigned short*)(ws + 16777216);   //    589,824 B (1152 rows: 64 pad)
  unsigned short* woutT = (unsigned short*)(ws + 17367040);   //    262,144 B
  unsigned short* zbf   = (unsigned short*)(ws + 17629184);   // 33,554,432 B (becomes t after scan3g)
  unsigned short* xbcbf = (unsigned short*)(ws + 51183616);   // 35,651,584 B
  float* dtraw          = (float*)(ws + 86835200);            //  4,194,304 B (Pp overlaps after k_convdt)
  float* Pp             = dtraw;                              //     65,536 B
  unsigned short* ylb   = (unsigned short*)(ws + 91029504);   // 33,554,432 B (bf16 y_local)
  float* convoBC        = (float*)(ws + 124583936);           //  4,194,304 B
  float* dtq            = (float*)(ws + 128778240);           //  4,194,304 B
  float* daq            = (float*)(ws + 132972544);           //  4,194,304 B  (total 137,166,848 B)

  k_cast_u<<<NROWS*DMODEL/1024, 256, 0, stream>>>(u, ubf);
  k_transpose2<<<(DINPROJ*DMODEL + DINNER*DMODEL)/256, 256, 0, stream>>>(W_in, W_out, wintT, woutT);

  // GEMM1: all 1088 cols as 9 y-tiles of 128 (tile 8 is half-pad, stores masked)
  k_gemm<1,4,DMODEL,9><<<(NROWS/128)*9, 512, 0, stream>>>(ubf, wintT, zbf, xbcbf, dtraw, nullptr, 0);

  // merged conv(B/C)+silu and dt/dA
  k_convdt<<<NROWS/64 + NROWS*NHEADS/256, 256, 0, stream>>>(xbcbf, conv_w, conv_b, convoBC,
                                                            dtraw, dt_bias, A_log, dtq, daq);

  k_scan1<<<BATCH*2*NCH, 256, 0, stream>>>(xbcbf, convoBC, dtq, daq, conv_w, conv_b, Dvec,
                                           ylb, chst, Pp);
  k_scan2<<<BATCH*NHEADS, 64, 0, stream>>>(chst, Pp);
  k_scan3g<<<BATCH*NCH*2, 512, 0, stream>>>(ylb, convoBC, daq, chst, zbf, norm_w);

  // GEMM2: N=256 as 2 y-tiles, XCD-grouped
  k_gemm<2,4,DINNER,2><<<(NROWS/128)*2, 512, 0, stream>>>(zbf, woutT, nullptr, nullptr, nullptr, out, DMODEL);
}

// Round 25
// 160.255 us; speedup vs baseline: 1.1022x; 1.0001x over previous
//
#include <hip/hip_runtime.h>
#include <hip/hip_bf16.h>
#include <math.h>

#define BATCH   8
#define SEQLEN  4096
#define DMODEL  256
#define DSTATE  16
#define NHEADS  32
#define HEADDIM 16
#define DINNER  512
#define CONVDIM 544
#define DINPROJ 1088
#define NROWS   (BATCH*SEQLEN)
#define CHUNK   64
#define NCH     (SEQLEN/CHUNK)   // 64

typedef __attribute__((ext_vector_type(8))) short short8;
typedef __attribute__((ext_vector_type(8))) unsigned short ushort8;
typedef __attribute__((ext_vector_type(4))) float f32x4;

__device__ __forceinline__ float bfu2f(unsigned short u){
  union { float f; unsigned int i; } x; x.i = ((unsigned int)u) << 16; return x.f;
}
__device__ __forceinline__ unsigned short f2bfu(float f){
  union { float f; unsigned int u; } v; v.f = f;
  v.u += 0x7fffu + ((v.u >> 16) & 1u);
  return (unsigned short)(v.u >> 16);
}

// ---------------- prep: cast u to bf16 AND transpose+cast both weights ----------------
#define NB_CAST (NROWS*DMODEL/1024)
#define NB_TR   ((DINPROJ*DMODEL + DINNER*DMODEL)/256)
__global__ __launch_bounds__(256) void k_prep(const float* __restrict__ u, unsigned short* __restrict__ ub,
                                              const float* __restrict__ Win,
                                              const float* __restrict__ Wout,
                                              unsigned short* __restrict__ WinT,
                                              unsigned short* __restrict__ WoutT){
  if (blockIdx.x < NB_CAST){
    int i = blockIdx.x*256 + threadIdx.x;
    float4 v = reinterpret_cast<const float4*>(u)[i];
    ushort4 o; o.x=f2bfu(v.x); o.y=f2bfu(v.y); o.z=f2bfu(v.z); o.w=f2bfu(v.w);
    reinterpret_cast<ushort4*>(ub)[i] = o;
  } else {
    int idx = (blockIdx.x - NB_CAST)*256 + threadIdx.x;
    const int N1 = DINPROJ*DMODEL;          // 278528
    if (idx < N1){
      int n = idx / DMODEL, k = idx - n*DMODEL;
      WinT[idx] = f2bfu(Win[(size_t)k*DINPROJ + n]);
    } else {
      int j = idx - N1;                     // < 131072
      int n = j / DINNER, k = j - n*DINNER;
      WoutT[j] = f2bfu(Wout[(size_t)k*DMODEL + n]);
    }
  }
}

// ---------------- bf16 MFMA GEMM: BK=64 single-buffer; NY y-tiles, XCD-grouped ----------------
template<int EPI, int WC, int K, int NY>
__global__ __launch_bounds__(WC*128) void k_gemm(
    const unsigned short* __restrict__ A,
    const unsigned short* __restrict__ BT,
    unsigned short* __restrict__ oz,
    unsigned short* __restrict__ oxbc,
    float* __restrict__ odtraw,
    float* __restrict__ of32, int Nout)
{
  constexpr int BN      = WC*32;
  constexpr int THREADS = WC*128;
  constexpr int NAI     = 1024/THREADS;
  constexpr int NBI     = (BN*8)/THREADS;
  __shared__ uint4 lds[(128 + BN)*8];
  const int tid = threadIdx.x;
  const int l   = tid & 63;
  const int w   = tid >> 6;
  const int wr  = w & 1, wc = w >> 1;
  int bx, by;
  if (NY == 1){ bx = blockIdx.x; by = 0; }
  else {
    int flat = blockIdx.x;
    int xcd = flat & 7;
    int grp = flat >> 3;
    by = grp % NY;
    bx = (grp / NY)*8 + xcd;
  }
  const int bm0 = bx * 128;
  const int bn0 = by * BN;
  const int fr  = l & 15, kq = l >> 4;
  f32x4 acc[4][2] = {};
  const int nK = K >> 6;
  for (int kt = 0; kt < nK; ++kt){
    const int k0 = kt << 6;
    #pragma unroll
    for (int i = 0; i < NAI; ++i){
      int idx = tid + i*THREADS;
      int row = idx >> 3, slot = idx & 7;
      uint4 v = *reinterpret_cast<const uint4*>(A + (size_t)(bm0+row)*K + k0 + slot*8);
      lds[row*8 + (slot ^ (row & 7))] = v;
    }
    #pragma unroll
    for (int i = 0; i < NBI; ++i){
      int idx = tid + i*THREADS;
      int row = idx >> 3, slot = idx & 7;
      uint4 v = *reinterpret_cast<const uint4*>(BT + (size_t)(bn0+row)*K + k0 + slot*8);
      lds[1024 + row*8 + (slot ^ (row & 7))] = v;
    }
    __syncthreads();
    short8 bf[2][2];
    #pragma unroll
    for (int kk = 0; kk < 2; ++kk){
      #pragma unroll
      for (int nf = 0; nf < 2; ++nf){
        int rb = wc*32 + nf*16 + fr;
        bf[kk][nf] = *reinterpret_cast<const short8*>(&lds[1024 + rb*8 + ((kk*4 + kq) ^ (rb & 7))]);
      }
    }
    #pragma unroll
    for (int mf = 0; mf < 4; ++mf){
      int ra = wr*64 + mf*16 + fr;
      #pragma unroll
      for (int kk = 0; kk < 2; ++kk){
        short8 af = *reinterpret_cast<const short8*>(&lds[ra*8 + ((kk*4 + kq) ^ (ra & 7))]);
        #pragma unroll
        for (int nf = 0; nf < 2; ++nf)
          acc[mf][nf] = __builtin_amdgcn_mfma_f32_16x16x32_bf16(af, bf[kk][nf], acc[mf][nf], 0, 0, 0);
      }
    }
    __syncthreads();
  }
  #pragma unroll
  for (int mf = 0; mf < 4; ++mf){
    #pragma unroll
    for (int nf = 0; nf < 2; ++nf){
      #pragma unroll
      for (int r = 0; r < 4; ++r){
        int m = bm0 + wr*64 + mf*16 + kq*4 + r;
        int n = bn0 + wc*32 + nf*16 + fr;
        float v = acc[mf][nf][r];
        if (EPI == 1){
          if (n < DINNER)                 oz[(size_t)m*DINNER + n] = f2bfu(v);
          else if (n < DINNER + CONVDIM)  oxbc[(size_t)m*CONVDIM + (n - DINNER)] = f2bfu(v);
          else if (n < DINPROJ)           odtraw[(size_t)m*NHEADS + (n - DINNER - CONVDIM)] = v;
          // n >= DINPROJ (pad tile): discard
        } else {
          of32[(size_t)m*Nout + n] = v;
        }
      }
    }
  }
}

// ---------------- merged: conv+silu (B/C channels) AND dt/dA precompute ----------------
__global__ __launch_bounds__(256) void k_convdt(const unsigned short* __restrict__ xbc,
                                                const float* __restrict__ cw,
                                                const float* __restrict__ cb,
                                                float* __restrict__ bco,
                                                const float* __restrict__ dtraw,
                                                const float* __restrict__ dt_bias,
                                                const float* __restrict__ A_log,
                                                float* __restrict__ dt_o,
                                                float* __restrict__ dA_o){
  const int tid = threadIdx.x;
  if (blockIdx.x < NROWS/64){
    const int j = tid & 31;
    const int rt = tid >> 5;
    const int r0 = blockIdx.x*64 + rt*8;
    const int ch = 512 + j;
    const int tloc = r0 & (SEQLEN-1);
    float wv0 = cw[ch*4+0], wv1 = cw[ch*4+1], wv2 = cw[ch*4+2], wv3 = cw[ch*4+3];
    const float bias = cb[ch];
    float xr[11];
    #pragma unroll
    for (int k = 0; k < 11; ++k){
      int r = r0 - 3 + k;
      xr[k] = (tloc - 3 + k < 0) ? 0.f : bfu2f(xbc[(size_t)r*CONVDIM + ch]);
    }
    #pragma unroll
    for (int i = 0; i < 8; ++i){
      float acc = fmaf(wv0, xr[i], fmaf(wv1, xr[i+1], fmaf(wv2, xr[i+2], fmaf(wv3, xr[i+3], bias))));
      bco[(size_t)(r0+i)*32 + j] = acc / (1.f + __expf(-acc));
    }
  } else {
    int i = (blockIdx.x - NROWS/64)*256 + tid;   // NROWS*NHEADS
    int h = i & (NHEADS-1);
    float x = dtraw[i] + dt_bias[h];
    float dt = (x > 20.f) ? x : log1pf(expf(x));
    dt_o[i] = dt;
    dA_o[i] = expf(-expf(A_log[h]) * dt);
  }
}

// ======== scan pass 1 (r11 form; y_local stored as bf16) ========
__global__ __launch_bounds__(256,4) void k_scan1(
    const unsigned short* __restrict__ xbc, const float* __restrict__ bc,
    const float* __restrict__ dta, const float* __restrict__ daa,
    const float* __restrict__ cwv, const float* __restrict__ cbv,
    const float* __restrict__ Dv,
    unsigned short* __restrict__ ylb, float* __restrict__ st, float* __restrict__ Pp)
{
  __shared__ float sBC[65*32];
  __shared__ float sdt[65*16];
  __shared__ float sda[65*16];
  const int tid = threadIdx.x;
  const int bid = blockIdx.x;
  const int qh = bid & 1;
  const int c  = (bid >> 1) & (NCH-1);
  const int b  = bid >> 7;
  const int w  = tid >> 6;
  const int l  = tid & 63;
  const int q  = qh*4 + w;
  const int hh = l >> 4, p = l & 15;
  const int h  = q*4 + hh;
  const size_t row0 = (size_t)b*SEQLEN + (size_t)c*CHUNK;
  const int xoff = q*64 + l;
  {
    const float* src = bc + row0*32;
    #pragma unroll
    for (int i = 0; i < 2; ++i){
      int idx = tid + i*256;
      *reinterpret_cast<float4*>(&sBC[idx*4]) = *reinterpret_cast<const float4*>(src + (size_t)idx*4);
    }
  }
  {
    int t = tid >> 2, g = (tid & 3)*4;
    *reinterpret_cast<float4*>(&sdt[t*16+g]) =
      *reinterpret_cast<const float4*>(dta + (row0+t)*NHEADS + qh*16 + g);
    *reinterpret_cast<float4*>(&sda[t*16+g]) =
      *reinterpret_cast<const float4*>(daa + (row0+t)*NHEADS + qh*16 + g);
  }
  const float cw0 = cwv[xoff*4+0], cw1 = cwv[xoff*4+1], cw2 = cwv[xoff*4+2], cw3 = cwv[xoff*4+3];
  const float cb0 = cbv[xoff];
  const float Dh = Dv[h];
  const int dIdx = w*4 + hh;
  float wA, wB, wC;
  if (c == 0){ wA = wB = wC = 0.f; }
  else {
    wA = bfu2f(xbc[(row0-3)*CONVDIM + xoff]);
    wB = bfu2f(xbc[(row0-2)*CONVDIM + xoff]);
    wC = bfu2f(xbc[(row0-1)*CONVDIM + xoff]);
  }
  float xq0 = bfu2f(xbc[(row0+0)*CONVDIM + xoff]);
  float xq1 = bfu2f(xbc[(row0+1)*CONVDIM + xoff]);
  float xq2 = bfu2f(xbc[(row0+2)*CONVDIM + xoff]);
  float xq3 = bfu2f(xbc[(row0+3)*CONVDIM + xoff]);
  __syncthreads();
  float BA[32], BB[32];
  #pragma unroll
  for (int k = 0; k < 8; ++k)
    *reinterpret_cast<float4*>(&BA[4*k]) = *reinterpret_cast<const float4*>(&sBC[4*k]);
  float dtA = sdt[dIdx], daA = sda[dIdx];
  float dtB, daB;
  float hs[16];
  #pragma unroll
  for (int n = 0; n < 16; ++n) hs[n] = 0.f;
  float cum = 1.f;

#define S1STEP(CUR, NXT, DTC, DAC, DTN, DAN, XQ, T) {                          \
    const int t_ = (T);                                                        \
    _Pragma("unroll")                                                          \
    for (int k = 0; k < 8; ++k)                                                \
      *reinterpret_cast<float4*>(&NXT[4*k]) =                                  \
        *reinterpret_cast<const float4*>(&sBC[(t_+1)*32 + 4*k]);               \
    DTN = sdt[(t_+1)*16 + dIdx]; DAN = sda[(t_+1)*16 + dIdx];                  \
    float xnew = bfu2f(xbc[(row0 + t_ + 4)*CONVDIM + xoff]);                   \
    float xc = fmaf(cw0, wA, fmaf(cw1, wB, fmaf(cw2, wC, fmaf(cw3, XQ, cb0))));\
    wA = wB; wB = wC; wC = XQ; XQ = xnew;                                      \
    float xs = xc / (1.f + __expf(-xc));                                       \
    float dx = DTC * xs;                                                       \
    float y_ = 0.f;                                                            \
    _Pragma("unroll")                                                          \
    for (int n = 0; n < 16; ++n) hs[n] = fmaf(DAC, hs[n], dx*CUR[n]);          \
    _Pragma("unroll")                                                          \
    for (int n = 0; n < 16; ++n) y_ = fmaf(hs[n], CUR[16+n], y_);              \
    cum *= DAC;                                                                \
    ylb[(row0 + t_)*DINNER + xoff] = f2bfu(y_ + Dh*xs);                        \
  }

  for (int T = 0; T < CHUNK; T += 4){
    S1STEP(BA, BB, dtA, daA, dtB, daB, xq0, T+0);
    S1STEP(BB, BA, dtB, daB, dtA, daA, xq1, T+1);
    S1STEP(BA, BB, dtA, daA, dtB, daB, xq2, T+2);
    S1STEP(BB, BA, dtB, daB, dtA, daA, xq3, T+3);
  }
#undef S1STEP
  float* sp = st + (((size_t)(b*NHEADS + h)*NCH + c)*16 + p)*16;
  #pragma unroll
  for (int k = 0; k < 4; ++k)
    *reinterpret_cast<float4*>(sp + 4*k) = make_float4(hs[4*k], hs[4*k+1], hs[4*k+2], hs[4*k+3]);
  if (p == 0) Pp[((size_t)b*NHEADS + h)*NCH + c] = cum;
}

// pass 2: inter-chunk scan; st[c] := hinit_c in place.
__global__ __launch_bounds__(64) void k_scan2(float* __restrict__ st, const float* __restrict__ Pp){
  const int bh = blockIdx.x;
  const int l = threadIdx.x;
  float* sb = st + (size_t)bh*NCH*256 + l*4;
  const float* pb = Pp + (size_t)bh*NCH;
  float4 carry = make_float4(0.f,0.f,0.f,0.f);
  float4 Hb[4]; float Pb[4];
  #pragma unroll
  for (int i = 0; i < 4; ++i){
    Hb[i] = *reinterpret_cast<const float4*>(sb + (size_t)i*256);
    Pb[i] = pb[i];
  }
  for (int c0 = 0; c0 < NCH; c0 += 4){
    #pragma unroll
    for (int i = 0; i < 4; ++i){
      const int cc = c0 + i;
      float4 Hc = Hb[i]; float Pc = Pb[i];
      if (cc + 4 < NCH){
        Hb[i] = *reinterpret_cast<const float4*>(sb + (size_t)(cc+4)*256);
        Pb[i] = pb[cc+4];
      }
      *reinterpret_cast<float4*>(sb + (size_t)cc*256) = carry;
      carry.x = fmaf(Pc, carry.x, Hc.x);
      carry.y = fmaf(Pc, carry.y, Hc.y);
      carry.z = fmaf(Pc, carry.z, Hc.z);
      carry.w = fmaf(Pc, carry.w, Hc.w);
    }
  }
}

// ======== pass 3 fused gate+RMSNorm, half-chunk split; tree cum ========
__global__ __launch_bounds__(512) void k_scan3g(
    const unsigned short* __restrict__ ylb, const float* __restrict__ bc,
    const float* __restrict__ daa, const float* __restrict__ st,
    unsigned short* __restrict__ zbf, const float* __restrict__ nw)
{
  __shared__ float sC[65*16];
  __shared__ float sda[65*32];
  __shared__ float sred[2][4][8];
  const int tid = threadIdx.x;
  const int bid = blockIdx.x;     // ((b*NCH + c)<<1) | half
  const int half = bid & 1;
  const int c = (bid >> 1) & (NCH-1);
  const int b = bid >> 7;
  const int T0 = half*32;
  const int w = tid >> 6;
  const int l = tid & 63;
  const int hh = l >> 4, p = l & 15;
  const int h = w*4 + hh;
  const size_t row0 = (size_t)b*SEQLEN + (size_t)c*CHUNK;
  const int xoff = w*64 + l;
  if (tid < 256){
    int t = tid >> 2, g = (tid & 3)*4;
    *reinterpret_cast<float4*>(&sC[t*16+g]) =
      *reinterpret_cast<const float4*>(bc + (row0+t)*32 + 16 + g);
  } else {
    int j = tid - 256;
    #pragma unroll
    for (int kk = 0; kk < 2; ++kk){
      int idx = j*2 + kk;
      int t = idx >> 3, g = (idx & 7)*4;
      *reinterpret_cast<float4*>(&sda[t*32+g]) =
        *reinterpret_cast<const float4*>(daa + (row0+t)*NHEADS + g);
    }
  }
  float hi[16];
  {
    const float* sp = st + (((size_t)(b*NHEADS + h)*NCH + c)*16 + p)*16;
    #pragma unroll
    for (int k = 0; k < 4; ++k){
      float4 v = *reinterpret_cast<const float4*>(sp + 4*k);
      hi[4*k] = v.x; hi[4*k+1] = v.y; hi[4*k+2] = v.z; hi[4*k+3] = v.w;
    }
  }
  const float nwv = nw[xoff];
  float yq0 = bfu2f(ylb[(row0+T0+0)*DINNER + xoff]);
  float yq1 = bfu2f(ylb[(row0+T0+1)*DINNER + xoff]);
  float yq2 = bfu2f(ylb[(row0+T0+2)*DINNER + xoff]);
  float yq3 = bfu2f(ylb[(row0+T0+3)*DINNER + xoff]);
  float zq0 = bfu2f(zbf[(row0+T0+0)*DINNER + xoff]);
  float zq1 = bfu2f(zbf[(row0+T0+1)*DINNER + xoff]);
  float zq2 = bfu2f(zbf[(row0+T0+2)*DINNER + xoff]);
  float zq3 = bfu2f(zbf[(row0+T0+3)*DINNER + xoff]);
  __syncthreads();
  float cum = 1.f;
  if (T0){
    float c0=1.f, c1=1.f, c2=1.f, c3=1.f;
    #pragma unroll
    for (int t = 0; t < 32; t += 4){
      c0 *= sda[(t+0)*32 + h];
      c1 *= sda[(t+1)*32 + h];
      c2 *= sda[(t+2)*32 + h];
      c3 *= sda[(t+3)*32 + h];
    }
    cum = (c0*c1)*(c2*c3);
  }
  float CA[16], CB[16];
  #pragma unroll
  for (int k = 0; k < 4; ++k)
    *reinterpret_cast<float4*>(&CA[4*k]) = *reinterpret_cast<const float4*>(&sC[T0*16 + 4*k]);
  float daA = sda[T0*32 + h], daB;

#define S3STEP(CUR, NXT, DAC, DAN, YQ, ZQ, TV, PS, T) {                        \
    const int t_ = (T);                                                        \
    _Pragma("unroll")                                                          \
    for (int k = 0; k < 4; ++k)                                                \
      *reinterpret_cast<float4*>(&NXT[4*k]) =                                  \
        *reinterpret_cast<const float4*>(&sC[(t_+1)*16 + 4*k]);                \
    DAN = sda[(t_+1)*32 + h];                                                  \
    float ynew = bfu2f(ylb[(row0 + t_ + 4)*DINNER + xoff]);                    \
    float znew = bfu2f(zbf[(row0 + t_ + 4)*DINNER + xoff]);                    \
    cum *= DAC;                                                                \
    float corr = 0.f;                                                          \
    _Pragma("unroll")                                                          \
    for (int n = 0; n < 16; ++n) corr = fmaf(hi[n], CUR[n], corr);             \
    float yv = YQ + cum*corr;                                                  \
    float sg = ZQ / (1.f + __expf(-ZQ));                                       \
    TV = yv * sg; PS = TV*TV;                                                  \
    YQ = ynew; ZQ = znew;                                                      \
  }

  for (int T = T0; T < T0 + 32; T += 4){
    float tv0, tv1, tv2, tv3, ps0, ps1, ps2, ps3;
    S3STEP(CA, CB, daA, daB, yq0, zq0, tv0, ps0, T+0);
    S3STEP(CB, CA, daB, daA, yq1, zq1, tv1, ps1, T+1);
    S3STEP(CA, CB, daA, daB, yq2, zq2, tv2, ps2, T+2);
    S3STEP(CB, CA, daB, daA, yq3, zq3, tv3, ps3, T+3);
    #pragma unroll
    for (int m = 1; m <= 32; m <<= 1){
      ps0 += __shfl_xor(ps0, m, 64);
      ps1 += __shfl_xor(ps1, m, 64);
      ps2 += __shfl_xor(ps2, m, 64);
      ps3 += __shfl_xor(ps3, m, 64);
    }
    const int gb = (T >> 2) & 1;
    if (l == 0){
      sred[gb][0][w] = ps0; sred[gb][1][w] = ps1;
      sred[gb][2][w] = ps2; sred[gb][3][w] = ps3;
    }
    __syncthreads();
    float ss[4];
    #pragma unroll
    for (int i = 0; i < 4; ++i){
      float4 ra = *reinterpret_cast<const float4*>(&sred[gb][i][0]);
      float4 rb = *reinterpret_cast<const float4*>(&sred[gb][i][4]);
      ss[i] = (ra.x+ra.y)+(ra.z+ra.w)+((rb.x+rb.y)+(rb.z+rb.w));
    }
    unsigned short* zp = zbf + (row0 + T)*DINNER + xoff;
    zp[0*DINNER] = f2bfu(tv0 * rsqrtf(ss[0]*(1.f/DINNER) + 1e-5f) * nwv);
    zp[1*DINNER] = f2bfu(tv1 * rsqrtf(ss[1]*(1.f/DINNER) + 1e-5f) * nwv);
    zp[2*DINNER] = f2bfu(tv2 * rsqrtf(ss[2]*(1.f/DINNER) + 1e-5f) * nwv);
    zp[3*DINNER] = f2bfu(tv3 * rsqrtf(ss[3]*(1.f/DINNER) + 1e-5f) * nwv);
  }
#undef S3STEP
}

extern "C" void kernel_launch(void* const* d_in, const int* in_sizes, int n_in,
                              void* d_out, int out_size, void* d_ws, size_t ws_size,
                              hipStream_t stream)
{
  const float* u       = (const float*)d_in[0];
  const float* W_in    = (const float*)d_in[1];
  const float* conv_w  = (const float*)d_in[2];
  const float* conv_b  = (const float*)d_in[3];
  const float* dt_bias = (const float*)d_in[4];
  const float* A_log   = (const float*)d_in[5];
  const float* Dvec    = (const float*)d_in[6];
  const float* norm_w  = (const float*)d_in[7];
  const float* W_out   = (const float*)d_in[8];
  float* out = (float*)d_out;
  char* ws = (char*)d_ws;

  unsigned short* ubf   = (unsigned short*)(ws + 0);          // 16,777,216 B (dead after GEMM1)
  float* chst           = (float*)(ws + 0);                   // 16,777,216 B (scan, overlaps ubf)
  unsigned short* wintT = (unsigned short*)(ws + 16777216);   //    589,824 B (1152 rows: 64 pad)
  unsigned short* woutT = (unsigned short*)(ws + 17367040);   //    262,144 B
  unsigned short* zbf   = (unsigned short*)(ws + 17629184);   // 33,554,432 B (becomes t after scan3g)
  unsigned short* xbcbf = (unsigned short*)(ws + 51183616);   // 35,651,584 B
  float* dtraw          = (float*)(ws + 86835200);            //  4,194,304 B (Pp overlaps after k_convdt)
  float* Pp             = dtraw;                              //     65,536 B
  unsigned short* ylb   = (unsigned short*)(ws + 91029504);   // 33,554,432 B (bf16 y_local)
  float* convoBC        = (float*)(ws + 124583936);           //  4,194,304 B
  float* dtq            = (float*)(ws + 128778240);           //  4,194,304 B
  float* daq            = (float*)(ws + 132972544);           //  4,194,304 B  (total 137,166,848 B)

  k_prep<<<NB_CAST + NB_TR, 256, 0, stream>>>(u, ubf, W_in, W_out, wintT, woutT);

  // GEMM1: all 1088 cols as 9 y-tiles of 128 (tile 8 is half-pad, stores masked)
  k_gemm<1,4,DMODEL,9><<<(NROWS/128)*9, 512, 0, stream>>>(ubf, wintT, zbf, xbcbf, dtraw, nullptr, 0);

  // merged conv(B/C)+silu and dt/dA
  k_convdt<<<NROWS/64 + NROWS*NHEADS/256, 256, 0, stream>>>(xbcbf, conv_w, conv_b, convoBC,
                                                            dtraw, dt_bias, A_log, dtq, daq);

  k_scan1<<<BATCH*2*NCH, 256, 0, stream>>>(xbcbf, convoBC, dtq, daq, conv_w, conv_b, Dvec,
                                           ylb, chst, Pp);
  k_scan2<<<BATCH*NHEADS, 64, 0, stream>>>(chst, Pp);
  k_scan3g<<<BATCH*NCH*2, 512, 0, stream>>>(ylb, convoBC, daq, chst, zbf, norm_w);

  // GEMM2: N=256 as 2 y-tiles, XCD-grouped
  k_gemm<2,4,DINNER,2><<<(NROWS/128)*2, 512, 0, stream>>>(zbf, woutT, nullptr, nullptr, nullptr, out, DMODEL);
}